// Round 5
// baseline (144.178 us; speedup 1.0000x reference)
//
#include <hip/hip_runtime.h>

// 44 independent tiny MLPs (1 -> 4 -> 8 -> 4 -> 1, relu x3, affine out),
// pointwise over B = 400000 samples. fp32 in/out.
//
// R1: VALUBusy 72%, HBM 24% -> VALU-bound (~54 us).
// R3: packed fp32 gave only ~12 us: v_pk_fma_f32 is TWO-PASS on CDNA4
//     (fp32 peak 157 TF == scalar rate) -> no cycle gain.
// R4/R5: layers 1-3 in packed f16 (v_pk_fma_f16 / v_pk_max_f16 are FULL-RATE:
//     2 f16 ops per 2-cycle wave64 instr), layer 4 in fp32 for accuracy
//     (|out| up to ~450; f16 accumulation there would blow the 0.99 budget).
//     Grid-stride loop (~8 float4 iters/thread) amortizes the per-thread
//     f32->f16 weight conversions. R5 fixes cvt_pkrtz return-type mismatch
//     via __builtin_bit_cast.

#define NP 44
#define BATCH 400000
#define B4C (BATCH / 4)   // 100000 float4 groups per population
#define GRIDX 49          // 49*256 = 12544 threads/pop -> ~8 float4 iters each

typedef float v2f __attribute__((ext_vector_type(2)));
typedef float v4f __attribute__((ext_vector_type(4)));
typedef _Float16 h2 __attribute__((ext_vector_type(2)));

__device__ __forceinline__ h2 hsplat(float s) {
    _Float16 h = (_Float16)s;
    return (h2){h, h};
}

// f32 pair -> packed f16 (v_cvt_pkrtz_f16_f32), with type laundering.
__device__ __forceinline__ h2 pk_cvt(float a, float b) {
    return __builtin_bit_cast(h2, __builtin_amdgcn_cvt_pkrtz(a, b));
}

// MLP forward for a PAIR of samples. Layers 1-3 packed f16, layer 4 fp32.
__device__ __forceinline__ v2f mlp_pair(h2 x,
        const h2* __restrict__ w1, const h2* __restrict__ w2,
        const h2* __restrict__ w3, const h2* __restrict__ c1,
        const h2* __restrict__ c2, const h2* __restrict__ c3,
        const float* __restrict__ w4, float c4) {
    const h2 zero = (h2){(_Float16)0.0f, (_Float16)0.0f};
    h2 h1[4], t2[8], h3[4];
#pragma unroll
    for (int i = 0; i < 4; ++i) {
        h2 a = __builtin_elementwise_fma(w1[i], x, c1[i]);   // v_pk_fma_f16
        h1[i] = __builtin_elementwise_max(a, zero);          // v_pk_max_f16
    }
#pragma unroll
    for (int i = 0; i < 8; ++i) {
        h2 a = c2[i];
#pragma unroll
        for (int k = 0; k < 4; ++k)
            a = __builtin_elementwise_fma(w2[i * 4 + k], h1[k], a);
        t2[i] = __builtin_elementwise_max(a, zero);
    }
#pragma unroll
    for (int i = 0; i < 4; ++i) {
        h2 a = c3[i];
#pragma unroll
        for (int k = 0; k < 8; ++k)
            a = __builtin_elementwise_fma(w3[i * 8 + k], t2[k], a);
        h3[i] = __builtin_elementwise_max(a, zero);
    }
    // Layer 4 in fp32: cvt_f32_f16 extracts + scalar fma, accuracy-critical.
    float o0 = c4, o1 = c4;
#pragma unroll
    for (int k = 0; k < 4; ++k) {
        o0 = fmaf(w4[k], (float)h3[k].x, o0);
        o1 = fmaf(w4[k], (float)h3[k].y, o1);
    }
    return (v2f){o0, o1};
}

__global__ __launch_bounds__(256) void mlp_fwd_kernel(
        const float* __restrict__ X,
        const float* __restrict__ lin1,
        const float* __restrict__ lin2,
        const float* __restrict__ lin3,
        const float* __restrict__ lin4,
        const float* __restrict__ b1,
        const float* __restrict__ b2,
        const float* __restrict__ b3,
        const float* __restrict__ b4,
        float* __restrict__ out) {
    const int l = blockIdx.y;   // population (wave-uniform -> s_load params)

    // f16x2 splat parameter registers (layers 1-3).
    h2 w1[4], c1[4], w2[32], c2[8], w3[32], c3[4];
    float w4[4];
#pragma unroll
    for (int i = 0; i < 4; ++i) {
        w1[i] = hsplat(lin1[l * 4 + i]);
        c1[i] = hsplat(b1[l * 4 + i]);
        c3[i] = hsplat(b3[l * 4 + i]);
        w4[i] = lin4[l * 4 + i];
    }
#pragma unroll
    for (int i = 0; i < 32; ++i) {
        w2[i] = hsplat(lin2[l * 32 + i]);
        w3[i] = hsplat(lin3[l * 32 + i]);
    }
#pragma unroll
    for (int i = 0; i < 8; ++i)
        c2[i] = hsplat(b2[l * 8 + i]);
    const float c4 = b4[l];

    const v4f* __restrict__ xin = (const v4f*)(X + (size_t)l * BATCH);
    v4f* po = (v4f*)(out + (size_t)l * BATCH);

    // Grid-stride over float4 groups: coalesced, amortizes weight setup.
    for (int j4 = blockIdx.x * blockDim.x + threadIdx.x; j4 < B4C;
         j4 += GRIDX * 256) {
        v4f x = xin[j4];
        h2 xa = pk_cvt(x.x, x.y);
        h2 xb = pk_cvt(x.z, x.w);
        v2f p0 = mlp_pair(xa, w1, w2, w3, c1, c2, c3, w4, c4);
        v2f p1 = mlp_pair(xb, w1, w2, w3, c1, c2, c3, w4, c4);
        v4f r = (v4f){p0.x, p0.y, p1.x, p1.y};
        __builtin_nontemporal_store(r, po + j4);
    }
}

extern "C" void kernel_launch(void* const* d_in, const int* in_sizes, int n_in,
                              void* d_out, int out_size, void* d_ws, size_t ws_size,
                              hipStream_t stream) {
    const float* X    = (const float*)d_in[0];
    const float* lin1 = (const float*)d_in[1];
    const float* lin2 = (const float*)d_in[2];
    const float* lin3 = (const float*)d_in[3];
    const float* lin4 = (const float*)d_in[4];
    const float* b1   = (const float*)d_in[5];
    const float* b2   = (const float*)d_in[6];
    const float* b3   = (const float*)d_in[7];
    const float* b4   = (const float*)d_in[8];
    float* out = (float*)d_out;

    dim3 block(256);
    dim3 grid(GRIDX, NP);   // grid-stride over 100000 float4s per population
    mlp_fwd_kernel<<<grid, block, 0, stream>>>(X, lin1, lin2, lin3, lin4,
                                               b1, b2, b3, b4, out);
}